// Round 1
// baseline (658.287 us; speedup 1.0000x reference)
//
#include <hip/hip_runtime.h>

#define NROWS 2048
#define MCOLS 2048
#define BN 16
#define BM 128

// workspace layout (float offsets)
#define OFF_AF 0
#define OFF_AS (OFF_AF + NROWS * 18)
#define OFF_BF (OFF_AS + NROWS * 18)
#define OFF_BS (OFF_BF + NROWS * 18)
#define OFF_FP (OFF_BS + NROWS * 18)
#define OFF_SL (OFF_FP + NROWS)
#define OFF_WP (OFF_SL + NROWS)
// packed weights layout (within OFF_WP), fluid then solid (+252)
#define WP_W1 0
#define WP_B1 162
#define WP_W2 171
#define WP_B2 225
#define WP_W3 231
#define WP_B3 249
#define WP_SOLID 252

__device__ __forceinline__ float fast_tanh(float x) {
    // tanh(x) = 1 - 2/(1 + e^{2x}),  e^{2x} = 2^{x * 2*log2(e)}
    float t = __builtin_amdgcn_exp2f(x * 2.8853900817779268f);
    return 1.0f - 2.0f * __builtin_amdgcn_rcpf(1.0f + t);
}

// Evaluate the shared 18->9->6->3 tail (with tanh on the 18-dim pre-activation
// A[m]+B[n]) for TWO m's at once so each weight LDS read feeds 2 FMAs.
__device__ __forceinline__ void mlp2(const float* __restrict__ sA,
                                     const float* __restrict__ sW, int woff,
                                     const float* B, int mA, int mB,
                                     float out[2][3]) {
    float hA[18], hB[18];
#pragma unroll
    for (int j = 0; j < 18; ++j) {
        hA[j] = fast_tanh(sA[mA * 18 + j] + B[j]);
        hB[j] = fast_tanh(sA[mB * 18 + j] + B[j]);
    }
    float gA[9], gB[9];
#pragma unroll
    for (int o = 0; o < 9; ++o) { float b = sW[woff + WP_B1 + o]; gA[o] = b; gB[o] = b; }
#pragma unroll
    for (int j = 0; j < 18; ++j) {
#pragma unroll
        for (int o = 0; o < 9; ++o) {
            float w = sW[woff + WP_W1 + j * 9 + o];
            gA[o] += hA[j] * w;
            gB[o] += hB[j] * w;
        }
    }
#pragma unroll
    for (int o = 0; o < 9; ++o) { gA[o] = fast_tanh(gA[o]); gB[o] = fast_tanh(gB[o]); }
    float qA[6], qB[6];
#pragma unroll
    for (int o = 0; o < 6; ++o) { float b = sW[woff + WP_B2 + o]; qA[o] = b; qB[o] = b; }
#pragma unroll
    for (int j = 0; j < 9; ++j) {
#pragma unroll
        for (int o = 0; o < 6; ++o) {
            float w = sW[woff + WP_W2 + j * 6 + o];
            qA[o] += gA[j] * w;
            qB[o] += gB[j] * w;
        }
    }
#pragma unroll
    for (int o = 0; o < 6; ++o) { qA[o] = fast_tanh(qA[o]); qB[o] = fast_tanh(qB[o]); }
#pragma unroll
    for (int o = 0; o < 3; ++o) { float b = sW[woff + WP_B3 + o]; out[0][o] = b; out[1][o] = b; }
#pragma unroll
    for (int j = 0; j < 6; ++j) {
#pragma unroll
        for (int o = 0; o < 3; ++o) {
            float w = sW[woff + WP_W3 + j * 3 + o];
            out[0][o] += qA[j] * w;
            out[1][o] += qB[j] * w;
        }
    }
}

__global__ void prep_kernel(const int* __restrict__ index,
                            const float* __restrict__ data,
                            const float* __restrict__ wf0, const float* __restrict__ bf0,
                            const float* __restrict__ sw0, const float* __restrict__ sb0,
                            const float* __restrict__ wf1, const float* __restrict__ bf1,
                            const float* __restrict__ wf2, const float* __restrict__ bf2,
                            const float* __restrict__ wf3, const float* __restrict__ bf3,
                            const float* __restrict__ sw1, const float* __restrict__ sb1,
                            const float* __restrict__ sw2, const float* __restrict__ sb2,
                            const float* __restrict__ sw3, const float* __restrict__ sb3,
                            float* __restrict__ wsp) {
    int i = blockIdx.x * blockDim.x + threadIdx.x;
    if (i < NROWS) {
        float d[7], cen[7];
#pragma unroll
        for (int c = 0; c < 7; ++c) d[c] = data[i * 7 + c];
        int ci = index[i];
#pragma unroll
        for (int c = 0; c < 7; ++c) cen[c] = data[ci * 7 + c];
#pragma unroll
        for (int j = 0; j < 18; ++j) {
            float af = 0.f;
#pragma unroll
            for (int c = 0; c < 7; ++c) af += d[c] * wf0[c * 18 + j];
            float as = d[0] * sw0[0 * 18 + j] + d[1] * sw0[1 * 18 + j] + d[2] * sw0[2 * 18 + j];
            float bf = bf0[j], bs = sb0[j];
#pragma unroll
            for (int c = 0; c < 3; ++c) bf -= cen[c] * wf0[c * 18 + j];
#pragma unroll
            for (int c = 0; c < 4; ++c) bf += cen[3 + c] * wf0[(7 + c) * 18 + j];
#pragma unroll
            for (int c = 0; c < 3; ++c) bs -= cen[c] * sw0[c * 18 + j];
#pragma unroll
            for (int c = 0; c < 4; ++c) bs += cen[3 + c] * sw0[(3 + c) * 18 + j];
            wsp[OFF_AF + i * 18 + j] = af;
            wsp[OFF_AS + i * 18 + j] = as;
            wsp[OFF_BF + i * 18 + j] = bf;
            wsp[OFF_BS + i * 18 + j] = bs;
        }
        wsp[OFF_FP + i] = (d[6] > 0.f) ? 1.f : 0.f;
        wsp[OFF_SL + i] = (d[6] < 1.f) ? 1.f : 0.f;
    }
    if (blockIdx.x == 0) {
        int t = threadIdx.x;
        float* wp = wsp + OFF_WP;
        for (int k = t; k < 162; k += 256) wp[WP_W1 + k] = wf1[k];
        for (int k = t; k < 9;   k += 256) wp[WP_B1 + k] = bf1[k];
        for (int k = t; k < 54;  k += 256) wp[WP_W2 + k] = wf2[k];
        for (int k = t; k < 6;   k += 256) wp[WP_B2 + k] = bf2[k];
        for (int k = t; k < 18;  k += 256) wp[WP_W3 + k] = wf3[k];
        for (int k = t; k < 3;   k += 256) wp[WP_B3 + k] = bf3[k];
        for (int k = t; k < 162; k += 256) wp[WP_SOLID + WP_W1 + k] = sw1[k];
        for (int k = t; k < 9;   k += 256) wp[WP_SOLID + WP_B1 + k] = sb1[k];
        for (int k = t; k < 54;  k += 256) wp[WP_SOLID + WP_W2 + k] = sw2[k];
        for (int k = t; k < 6;   k += 256) wp[WP_SOLID + WP_B2 + k] = sb2[k];
        for (int k = t; k < 18;  k += 256) wp[WP_SOLID + WP_W3 + k] = sw3[k];
        for (int k = t; k < 3;   k += 256) wp[WP_SOLID + WP_B3 + k] = sb3[k];
    }
}

__global__ __launch_bounds__(256)
void main_kernel(const int* __restrict__ mask,
                 const float* __restrict__ wsp,
                 float* __restrict__ out) {
    __shared__ float sAf[BM * 18];
    __shared__ float sAs[BM * 18];
    __shared__ float sW[504];
    __shared__ float sFp[BM];
    __shared__ float sSl[BM];
    const int m0 = blockIdx.x * BM;
    const int n0 = blockIdx.y * BN;
    const int tid = threadIdx.x;
    for (int idx = tid; idx < BM * 18; idx += 256) {
        sAf[idx] = wsp[OFF_AF + m0 * 18 + idx];
        sAs[idx] = wsp[OFF_AS + m0 * 18 + idx];
    }
    for (int idx = tid; idx < 504; idx += 256) sW[idx] = wsp[OFF_WP + idx];
    for (int idx = tid; idx < BM; idx += 256) {
        sFp[idx] = wsp[OFF_FP + m0 + idx];
        sSl[idx] = wsp[OFF_SL + m0 + idx];
    }
    __syncthreads();

    const int tx = tid & 15;
    const int ty = tid >> 4;
    const int n = n0 + ty;
    float Bf[18], Bs[18];
#pragma unroll
    for (int j = 0; j < 18; ++j) {
        Bf[j] = wsp[OFF_BF + n * 18 + j];
        Bs[j] = wsp[OFF_BS + n * 18 + j];
    }
    float p0 = 0.f, p1 = 0.f, p2 = 0.f;
    const int* mrow = mask + (size_t)n * MCOLS + m0;

#pragma unroll 1
    for (int kk = 0; kk < BM / 16; kk += 2) {
        const int mA = tx + kk * 16;
        const int mB = mA + 16;
        const int ga = mrow[mA];
        const int gb = mrow[mB];
        float x[2][3], y[2][3];
        mlp2(sAf, sW, 0,        Bf, mA, mB, x);
        mlp2(sAs, sW, WP_SOLID, Bs, mA, mB, y);
        const float fmA = ga ? sFp[mA] : 0.f;
        const float fmB = gb ? sFp[mB] : 0.f;
        const float smA = ga ? sSl[mA] : 0.f;
        const float smB = gb ? sSl[mB] : 0.f;
        p0 += fmA * x[0][0] + fmB * x[1][0] + smA * y[0][0] + smB * y[1][0];
        p1 += fmA * x[0][1] + fmB * x[1][1] + smA * y[0][1] + smB * y[1][1];
        p2 += fmA * x[0][2] + fmB * x[1][2] + smA * y[0][2] + smB * y[1][2];
    }

#pragma unroll
    for (int off = 1; off < 16; off <<= 1) {
        p0 += __shfl_xor(p0, off, 16);
        p1 += __shfl_xor(p1, off, 16);
        p2 += __shfl_xor(p2, off, 16);
    }
    if (tx == 0) {
        atomicAdd(&out[n * 3 + 0], p0);
        atomicAdd(&out[n * 3 + 1], p1);
        atomicAdd(&out[n * 3 + 2], p2);
    }
}

extern "C" void kernel_launch(void* const* d_in, const int* in_sizes, int n_in,
                              void* d_out, int out_size, void* d_ws, size_t ws_size,
                              hipStream_t stream) {
    const int*   mask  = (const int*)d_in[0];
    const int*   index = (const int*)d_in[1];
    const float* data  = (const float*)d_in[2];
    const float* wf0   = (const float*)d_in[3];
    const float* bf0   = (const float*)d_in[4];
    const float* wf1   = (const float*)d_in[5];
    const float* bf1   = (const float*)d_in[6];
    const float* wf2   = (const float*)d_in[7];
    const float* bf2   = (const float*)d_in[8];
    const float* wf3   = (const float*)d_in[9];
    const float* bf3   = (const float*)d_in[10];
    const float* sw0   = (const float*)d_in[11];
    const float* sb0   = (const float*)d_in[12];
    const float* sw1   = (const float*)d_in[13];
    const float* sb1   = (const float*)d_in[14];
    const float* sw2   = (const float*)d_in[15];
    const float* sb2   = (const float*)d_in[16];
    const float* sw3   = (const float*)d_in[17];
    const float* sb3   = (const float*)d_in[18];
    float* wsp = (float*)d_ws;
    float* out = (float*)d_out;

    hipMemsetAsync(d_out, 0, (size_t)out_size * sizeof(float), stream);
    prep_kernel<<<dim3(8), dim3(256), 0, stream>>>(
        index, data, wf0, bf0, sw0, sb0, wf1, bf1, wf2, bf2, wf3, bf3,
        sw1, sb1, sw2, sb2, sw3, sb3, wsp);
    main_kernel<<<dim3(MCOLS / BM, NROWS / BN), dim3(256), 0, stream>>>(mask, wsp, out);
}